// Round 8
// baseline (97.899 us; speedup 1.0000x reference)
//
#include <hip/hip_runtime.h>
#include <stdint.h>

#define T_SEQ 4096
#define NB 2
#define D_MODEL 2048
#define HD 128

typedef __attribute__((ext_vector_type(4)))  float f32x4;
typedef __attribute__((ext_vector_type(16))) float f32x16;
typedef __attribute__((ext_vector_type(8)))  short bf16x8;
typedef __attribute__((ext_vector_type(4)))  unsigned u32x4;

#define LAMBDA_INIT 0.7836057665316244f
#define OUT_SCALE   0.21639423346837556f

__device__ __forceinline__ unsigned short f2bf(float f) {
  unsigned int u = __float_as_uint(f);
  u += 0x7FFFu + ((u >> 16) & 1u);
  return (unsigned short)(u >> 16);
}
__device__ __forceinline__ float bf2f(unsigned short h) {
  return __uint_as_float(((unsigned int)h) << 16);
}
__device__ __forceinline__ unsigned cvt_pk_bf16(float a, float b) {
  unsigned r;
  asm("v_cvt_pk_bf16_f32 %0, %1, %2" : "=v"(r) : "v"(a), "v"(b));
  return r;
}
__device__ __forceinline__ void gload16(const void* g, void* l) {
  __builtin_amdgcn_global_load_lds(
      (const __attribute__((address_space(1))) unsigned int*)g,
      (__attribute__((address_space(3))) unsigned int*)l, 16, 0, 0);
}

// ---------------- Kernel 0: pre-pack W into per-k-slab LDS images ---------
// wT[(which*32 + slab)*8192 + (q*128 + n)*8 + e] = bf16( w[k][n] * scale ),
// k = slab*64 + q*8 + e.  q-scale 0.125 folded for which==0 (exact pow2).
__global__ __launch_bounds__(256) void wtrans(
    const float* __restrict__ wq, const float* __restrict__ wk,
    const float* __restrict__ wv, unsigned short* __restrict__ wT)
{
  const int which = blockIdx.y;
  const int s = blockIdx.x;                     // k-slab 0..31
  const float* w = (which == 0) ? wq : ((which == 1) ? wk : wv);
  const float scale = (which == 0) ? 0.125f : 1.0f;
  const int tid = threadIdx.x;
  #pragma unroll
  for (int j = 0; j < 4; ++j) {
    int cell = j * 256 + tid;                   // 0..1023
    int q = cell >> 7, n = cell & 127;
    int kb = s * 64 + q * 8;
    float v[8];
    #pragma unroll
    for (int e = 0; e < 8; ++e) v[e] = w[(size_t)(kb + e) * HD + n] * scale;
    u32x4 pk = { cvt_pk_bf16(v[0], v[1]), cvt_pk_bf16(v[2], v[3]),
                 cvt_pk_bf16(v[4], v[5]), cvt_pk_bf16(v[6], v[7]) };
    *reinterpret_cast<u32x4*>(&wT[(size_t)(which * 32 + s) * 8192 + (size_t)cell * 8]) = pk;
  }
}

// ---------------- Kernel 1: QKV projection (dbuf, BK=64, DMA B-tiles) -----
// M=64, N=128, grid (128,3), 4 waves (2m x 2n), 1 barrier per 64-k step.
// LDS k-major: A [8 q][64 row] cells, B [8 q][128 n] cells (16B cells).
__global__ __launch_bounds__(256, 2) void qkv_proj(
    const float* __restrict__ x, const unsigned short* __restrict__ wT,
    unsigned short* __restrict__ qb, unsigned short* __restrict__ kS,
    unsigned short* __restrict__ vS)
{
  __shared__ __align__(16) unsigned short Ab[2][4096];   // 2 x 8KB
  __shared__ __align__(16) unsigned short Bb[2][8192];   // 2 x 16KB
  const int which = blockIdx.y;
  const int m0 = blockIdx.x * 64;
  const int tid = threadIdx.x;
  const int lane = tid & 63, wid = tid >> 6;
  const int wm = wid >> 1, wn = wid & 1;        // wave tile 32(m) x 64(n)
  const int fr = lane & 15, fq = lane >> 4;

  const unsigned short* wslab = wT + (size_t)which * 32 * 8192;

  // A staging: thread owns cell q=tid>>5 of rows (tid&31) and (tid&31)+32
  const int arow = tid & 31, aq = tid >> 5;
  const float* xa = x + (size_t)(m0 + arow) * D_MODEL + aq * 8;
  const float* xb = xa + (size_t)32 * D_MODEL;

  f32x4 acc[2][4];
  #pragma unroll
  for (int i = 0; i < 2; ++i)
    #pragma unroll
    for (int j = 0; j < 4; ++j) acc[i][j] = (f32x4){0.f, 0.f, 0.f, 0.f};

  // prologue: stage iter 0 (A via regs, B via DMA), prefetch A regs iter 1
  {
    f32x4 u0 = *reinterpret_cast<const f32x4*>(xa);
    f32x4 u1 = *reinterpret_cast<const f32x4*>(xa + 4);
    f32x4 u2 = *reinterpret_cast<const f32x4*>(xb);
    f32x4 u3 = *reinterpret_cast<const f32x4*>(xb + 4);
    u32x4 c0 = { cvt_pk_bf16(u0[0], u0[1]), cvt_pk_bf16(u0[2], u0[3]),
                 cvt_pk_bf16(u1[0], u1[1]), cvt_pk_bf16(u1[2], u1[3]) };
    u32x4 c1 = { cvt_pk_bf16(u2[0], u2[1]), cvt_pk_bf16(u2[2], u2[3]),
                 cvt_pk_bf16(u3[0], u3[1]), cvt_pk_bf16(u3[2], u3[3]) };
    *reinterpret_cast<u32x4*>(&Ab[0][(size_t)(aq * 64 + arow) * 8]) = c0;
    *reinterpret_cast<u32x4*>(&Ab[0][(size_t)(aq * 64 + arow + 32) * 8]) = c1;
    #pragma unroll
    for (int j = 0; j < 4; ++j) {
      int ch = wid * 4 + j;
      gload16(wslab + (size_t)ch * 512 + (size_t)lane * 8, (char*)&Bb[0][ch * 512]);
    }
  }
  f32x4 a0 = *reinterpret_cast<const f32x4*>(xa + 64);
  f32x4 a1 = *reinterpret_cast<const f32x4*>(xa + 68);
  f32x4 a2 = *reinterpret_cast<const f32x4*>(xb + 64);
  f32x4 a3 = *reinterpret_cast<const f32x4*>(xb + 68);
  __syncthreads();

  for (int it = 0; it < 32; ++it) {
    const int cur = it & 1;
    if (it < 31) {
      // B DMA for next slab (flies under MFMA; barrier drains vmcnt)
      #pragma unroll
      for (int j = 0; j < 4; ++j) {
        int ch = wid * 4 + j;
        gload16(wslab + (size_t)(it + 1) * 8192 + (size_t)ch * 512 + (size_t)lane * 8,
                (char*)&Bb[cur ^ 1][ch * 512]);
      }
      // A write for next slab from prefetched regs
      u32x4 c0 = { cvt_pk_bf16(a0[0], a0[1]), cvt_pk_bf16(a0[2], a0[3]),
                   cvt_pk_bf16(a1[0], a1[1]), cvt_pk_bf16(a1[2], a1[3]) };
      u32x4 c1 = { cvt_pk_bf16(a2[0], a2[1]), cvt_pk_bf16(a2[2], a2[3]),
                   cvt_pk_bf16(a3[0], a3[1]), cvt_pk_bf16(a3[2], a3[3]) };
      *reinterpret_cast<u32x4*>(&Ab[cur ^ 1][(size_t)(aq * 64 + arow) * 8]) = c0;
      *reinterpret_cast<u32x4*>(&Ab[cur ^ 1][(size_t)(aq * 64 + arow + 32) * 8]) = c1;
      if (it < 30) {
        const int kn = (it + 2) * 64;
        a0 = *reinterpret_cast<const f32x4*>(xa + kn);
        a1 = *reinterpret_cast<const f32x4*>(xa + kn + 4);
        a2 = *reinterpret_cast<const f32x4*>(xb + kn);
        a3 = *reinterpret_cast<const f32x4*>(xb + kn + 4);
      }
    }
    // fragment reads (k-major: 256B-contiguous per 16-lane group)
    bf16x8 ah[2][2], bh[2][4];
    #pragma unroll
    for (int mi = 0; mi < 2; ++mi) {
      int row = wm * 32 + mi * 16 + fr;
      ah[mi][0] = *reinterpret_cast<bf16x8*>(&Ab[cur][(size_t)(fq * 64 + row) * 8]);
      ah[mi][1] = *reinterpret_cast<bf16x8*>(&Ab[cur][(size_t)((4 + fq) * 64 + row) * 8]);
    }
    #pragma unroll
    for (int ni = 0; ni < 4; ++ni) {
      int nrow = wn * 64 + ni * 16 + fr;
      bh[0][ni] = *reinterpret_cast<bf16x8*>(&Bb[cur][(size_t)(fq * 128 + nrow) * 8]);
      bh[1][ni] = *reinterpret_cast<bf16x8*>(&Bb[cur][(size_t)((4 + fq) * 128 + nrow) * 8]);
    }
    #pragma unroll
    for (int kk = 0; kk < 2; ++kk)
      #pragma unroll
      for (int mi = 0; mi < 2; ++mi)
        #pragma unroll
        for (int ni = 0; ni < 4; ++ni)
          acc[mi][ni] = __builtin_amdgcn_mfma_f32_16x16x32_bf16(ah[mi][kk], bh[kk][ni], acc[mi][ni], 0, 0, 0);
    __syncthreads();
  }
  // epilogue: q row-major (scale already folded in wT); K/V fragment scatter
  #pragma unroll
  for (int mi = 0; mi < 2; ++mi)
    #pragma unroll
    for (int ni = 0; ni < 4; ++ni) {
      int n = wn * 64 + ni * 16 + fr;
      #pragma unroll
      for (int r = 0; r < 4; ++r) {
        int m = m0 + wm * 32 + mi * 16 + fq * 4 + r;
        float vv = acc[mi][ni][r];
        int bb = m >> 12, tt = m & 4095;
        int kt = tt >> 5, kvl = tt & 31;
        if (which == 0) {
          qb[(size_t)m * HD + n] = f2bf(vv);
        } else if (which == 1) {
          int g = n >> 6, hl = n & 63;
          int ks = hl >> 4, r8 = (hl >> 3) & 1, e = hl & 7;
          size_t idx = ((((((size_t)bb * 128 + kt) * 2 + g) * 4) + ks) << 9)
                     + (size_t)(kvl + 32 * r8) * 8 + e;
          kS[idx] = f2bf(vv);
        } else {
          int f = kvl >> 4, r8 = (kvl >> 3) & 1, e = kvl & 7;
          int vcb = n >> 5;
          size_t idx = (((((size_t)bb * 128 + kt) * 8) + vcb * 2 + f) << 9)
                     + (size_t)((n & 31) + 32 * r8) * 8 + e;
          vS[idx] = f2bf(vv);
        }
      }
    }
}

// ---------------- Kernel 2: per-wave flash partials (unchanged R7) --------
template<int LOG2S>
__global__ __launch_bounds__(256, 2) void diff_attn_part(
    const unsigned short* __restrict__ qb, const unsigned short* __restrict__ kS,
    const unsigned short* __restrict__ vS,
    unsigned short* __restrict__ po, float* __restrict__ pm, float* __restrict__ pl)
{
  constexpr int S = 1 << LOG2S;
  const int tid = threadIdx.x, lane = tid & 63, wid = tid >> 6;
  const int wave_id = blockIdx.x * 4 + wid;
  const int sp = wave_id & (S - 1);
  const int g  = (wave_id >> LOG2S) & 1;
  const int qt_raw = (wave_id >> (LOG2S + 1)) & 127;
  const int b  = wave_id >> (LOG2S + 8);
  const int qt = 127 - qt_raw;                  // heavy-first scheduling
  const int slot = (((b * 128 + qt) * 2 + g) << LOG2S) + sp;
  const int lq = lane & 31, lh = lane >> 5;
  const int q0 = qt * 32;
  const int n  = qt + 1;
  const int kt0 = (n * sp) >> LOG2S;
  const int kt1 = (n * (sp + 1)) >> LOG2S;

  bf16x8 qf[4];
  const unsigned short* qp = qb + ((size_t)b * T_SEQ + q0 + lq) * HD + g * 64 + lh * 8;
  #pragma unroll
  for (int ks = 0; ks < 4; ++ks) qf[ks] = *reinterpret_cast<const bf16x8*>(qp + ks * 16);

  f32x16 acc[4];
  #pragma unroll
  for (int v = 0; v < 4; ++v)
    #pragma unroll
    for (int r = 0; r < 16; ++r) acc[v][r] = 0.f;
  float mrun = -1e30f, lrun = 0.f;

  const unsigned short* kbase = kS + ((size_t)(b * 128) * 2 + g) * 4 * 512 + lane * 8;
  const unsigned short* vbase = vS + (size_t)(b * 128) * 8 * 512 + lane * 8;
  #define KFRAG(kt, ks) (kbase + ((size_t)(kt) * 8 + (ks)) * 512)
  #define VFRAG(kt, f)  (vbase + ((size_t)(kt) * 8 + (f)) * 512)

  bf16x8 kf[4];
  if (kt0 < kt1) {
    #pragma unroll
    for (int ks = 0; ks < 4; ++ks)
      kf[ks] = *reinterpret_cast<const bf16x8*>(KFRAG(kt0, ks));
  }

  for (int kt = kt0; kt < kt1; ++kt) {
    bf16x8 vfa[4], vfb[4];
    #pragma unroll
    for (int vcb = 0; vcb < 4; ++vcb) {
      vfa[vcb] = *reinterpret_cast<const bf16x8*>(VFRAG(kt, vcb * 2));
      vfb[vcb] = *reinterpret_cast<const bf16x8*>(VFRAG(kt, vcb * 2 + 1));
    }
    bf16x8 kfn[4];
    const bool more = (kt + 1 < kt1);
    if (more) {
      #pragma unroll
      for (int ks = 0; ks < 4; ++ks)
        kfn[ks] = *reinterpret_cast<const bf16x8*>(KFRAG(kt + 1, ks));
    }
    f32x16 sc;
    #pragma unroll
    for (int r = 0; r < 16; ++r) sc[r] = 0.f;
    #pragma unroll
    for (int ks = 0; ks < 4; ++ks)
      sc = __builtin_amdgcn_mfma_f32_32x32x16_bf16(kf[ks], qf[ks], sc, 0, 0, 0);

    float p[16];
    if (kt == n - 1) {
      #pragma unroll
      for (int r = 0; r < 16; ++r) {
        int rloc = (r & 3) + 8 * (r >> 2) + 4 * lh;
        p[r] = (rloc > lq) ? -1e30f : sc[r];
      }
    } else {
      #pragma unroll
      for (int r = 0; r < 16; ++r) p[r] = sc[r];
    }
    float t16[16];
    #pragma unroll
    for (int r = 0; r < 16; ++r) t16[r] = p[r];
    #pragma unroll
    for (int st = 8; st >= 1; st >>= 1)
      #pragma unroll
      for (int r = 0; r < 8; ++r)
        if (r < st) t16[r] = fmaxf(t16[r], t16[r + st]);
    float pmax = fmaxf(t16[0], __shfl_xor(t16[0], 32));
    if (__any(pmax > mrun + 8.f)) {
      float mn = fmaxf(mrun, pmax);
      float al = __expf(mrun - mn);
      lrun *= al;
      #pragma unroll
      for (int v = 0; v < 4; ++v)
        #pragma unroll
        for (int r = 0; r < 16; ++r) acc[v][r] *= al;
      mrun = mn;
    }
    float psum;
    {
      float s16[16];
      #pragma unroll
      for (int r = 0; r < 16; ++r) { p[r] = __expf(p[r] - mrun); s16[r] = p[r]; }
      #pragma unroll
      for (int st = 8; st >= 1; st >>= 1)
        #pragma unroll
        for (int r = 0; r < 8; ++r)
          if (r < st) s16[r] += s16[r + st];
      psum = s16[0];
    }
    lrun += psum + __shfl_xor(psum, 32);

    unsigned A0 = cvt_pk_bf16(p[0],  p[1]),  A1 = cvt_pk_bf16(p[2],  p[3]);
    unsigned A2 = cvt_pk_bf16(p[4],  p[5]),  A3 = cvt_pk_bf16(p[6],  p[7]);
    unsigned A4 = cvt_pk_bf16(p[8],  p[9]),  A5 = cvt_pk_bf16(p[10], p[11]);
    unsigned A6 = cvt_pk_bf16(p[12], p[13]), A7 = cvt_pk_bf16(p[14], p[15]);
    unsigned pA0 = (unsigned)__shfl_xor((int)A0, 32);
    unsigned pA1 = (unsigned)__shfl_xor((int)A1, 32);
    unsigned pA2 = (unsigned)__shfl_xor((int)A2, 32);
    unsigned pA3 = (unsigned)__shfl_xor((int)A3, 32);
    unsigned pA4 = (unsigned)__shfl_xor((int)A4, 32);
    unsigned pA5 = (unsigned)__shfl_xor((int)A5, 32);
    unsigned pA6 = (unsigned)__shfl_xor((int)A6, 32);
    unsigned pA7 = (unsigned)__shfl_xor((int)A7, 32);
    u32x4 w0, w1;
    w0[0] = lh ? pA2 : A0;  w0[1] = lh ? pA3 : A1;
    w0[2] = lh ? A2  : pA0; w0[3] = lh ? A3  : pA1;
    w1[0] = lh ? pA6 : A4;  w1[1] = lh ? pA7 : A5;
    w1[2] = lh ? A6  : pA4; w1[3] = lh ? A7  : pA5;
    bf16x8 pb0 = *reinterpret_cast<bf16x8*>(&w0);
    bf16x8 pb1 = *reinterpret_cast<bf16x8*>(&w1);
    #pragma unroll
    for (int vcb = 0; vcb < 4; ++vcb) {
      acc[vcb] = __builtin_amdgcn_mfma_f32_32x32x16_bf16(vfa[vcb], pb0, acc[vcb], 0, 0, 0);
      acc[vcb] = __builtin_amdgcn_mfma_f32_32x32x16_bf16(vfb[vcb], pb1, acc[vcb], 0, 0, 0);
    }
    if (more) {
      #pragma unroll
      for (int ks = 0; ks < 4; ++ks) kf[ks] = kfn[ks];
    }
  }
  #undef KFRAG
  #undef VFRAG
  const size_t pbase = (size_t)slot * (HD * 32);
  #pragma unroll
  for (int vcb = 0; vcb < 4; ++vcb)
    #pragma unroll
    for (int r = 0; r < 16; ++r) {
      int vc = vcb * 32 + (r & 3) + 8 * (r >> 2) + 4 * lh;
      po[pbase + (size_t)vc * 32 + lq] = f2bf(acc[vcb][r]);
    }
  if (lane < 32) {
    pm[slot * 32 + lq] = mrun;
    pl[slot * 32 + lq] = lrun;
  }
}

// ---------------- Kernel 3: merge partials (unchanged R7) -----------------
template<int LOG2S>
__global__ __launch_bounds__(256) void diff_merge(
    const unsigned short* __restrict__ po, const float* __restrict__ pm,
    const float* __restrict__ pl,
    const float* __restrict__ lq1, const float* __restrict__ lq2,
    const float* __restrict__ lk1, const float* __restrict__ lk2,
    const float* __restrict__ lnw, float* __restrict__ out)
{
  constexpr int S = 1 << LOG2S;
  __shared__ float red[4][32];
  const int tid = threadIdx.x, lane = tid & 63, wid = tid >> 6;
  const int q = tid & 31, vg = tid >> 5;
  const int bq = blockIdx.x;
  const int b = bq >> 7, qt = bq & 127;

  float la = lq1[lane] * lk1[lane];
  float lb = lq2[lane] * lk2[lane];
  #pragma unroll
  for (int off = 32; off >= 1; off >>= 1) {
    la += __shfl_xor(la, off);
    lb += __shfl_xor(lb, off);
  }
  const float lam = __expf(la) - __expf(lb) + LAMBDA_INIT;

  const int p1 = (bq * 2 + 0) * S;
  const int p2 = (bq * 2 + 1) * S;
  float w1[S], w2[S];
  {
    float ms[S];
    #pragma unroll
    for (int s = 0; s < S; ++s) ms[s] = pm[(p1 + s) * 32 + q];
    float M = ms[0];
    #pragma unroll
    for (int s = 1; s < S; ++s) M = fmaxf(M, ms[s]);
    float L = 0.f;
    #pragma unroll
    for (int s = 0; s < S; ++s) { w1[s] = __expf(ms[s] - M); L += w1[s] * pl[(p1 + s) * 32 + q]; }
    float inv = 1.f / L;
    #pragma unroll
    for (int s = 0; s < S; ++s) w1[s] *= inv;
  }
  {
    float ms[S];
    #pragma unroll
    for (int s = 0; s < S; ++s) ms[s] = pm[(p2 + s) * 32 + q];
    float M = ms[0];
    #pragma unroll
    for (int s = 1; s < S; ++s) M = fmaxf(M, ms[s]);
    float L = 0.f;
    #pragma unroll
    for (int s = 0; s < S; ++s) { w2[s] = __expf(ms[s] - M); L += w2[s] * pl[(p2 + s) * 32 + q]; }
    float inv = lam / L;
    #pragma unroll
    for (int s = 0; s < S; ++s) w2[s] *= inv;
  }
  float d[16], ss = 0.f;
  #pragma unroll
  for (int i = 0; i < 16; ++i) {
    int vc = vg * 16 + i;
    float a1 = 0.f, a2 = 0.f;
    #pragma unroll
    for (int s = 0; s < S; ++s) {
      a1 += w1[s] * bf2f(po[(size_t)(p1 + s) * (HD * 32) + (size_t)vc * 32 + q]);
      a2 += w2[s] * bf2f(po[(size_t)(p2 + s) * (HD * 32) + (size_t)vc * 32 + q]);
    }
    d[i] = a1 - a2;
    ss += d[i] * d[i];
  }
  ss += __shfl_xor(ss, 32);
  if (lane < 32) red[wid][q] = ss;
  __syncthreads();
  float tot = red[0][q] + red[1][q] + red[2][q] + red[3][q];
  float rinv = 1.f / sqrtf(tot * (1.0f / HD) + 1e-5f);
  float* op = out + ((size_t)b * T_SEQ + qt * 32 + q) * HD + vg * 16;
  #pragma unroll
  for (int i = 0; i < 16; ++i) op[i] = OUT_SCALE * d[i] * rinv * lnw[vg * 16 + i];
}

extern "C" void kernel_launch(void* const* d_in, const int* in_sizes, int n_in,
                              void* d_out, int out_size, void* d_ws, size_t ws_size,
                              hipStream_t stream) {
  const float* x   = (const float*)d_in[0];
  const float* wq  = (const float*)d_in[1];
  const float* wk  = (const float*)d_in[2];
  const float* wv  = (const float*)d_in[3];
  const float* lq1 = (const float*)d_in[4];
  const float* lq2 = (const float*)d_in[5];
  const float* lk1 = (const float*)d_in[6];
  const float* lk2 = (const float*)d_in[7];
  const float* lnw = (const float*)d_in[8];
  float* out = (float*)d_out;

  const size_t N = (size_t)NB * T_SEQ * HD;     // 1,048,576
  const size_t WTN = (size_t)3 * 32 * 8192;     // 786,432
  int log2S = 3;
  for (; log2S > 0; --log2S) {
    size_t parts = ((size_t)NB * 128 * 2) << log2S;
    size_t need = 3 * N * 2 + WTN * 2 + parts * (HD * 32) * 2 + parts * 32 * 8;
    if (need <= ws_size) break;
  }
  const size_t parts = ((size_t)NB * 128 * 2) << log2S;

  unsigned short* qb = (unsigned short*)d_ws;
  unsigned short* kS = qb + N;
  unsigned short* vS = kS + N;
  unsigned short* wT = vS + N;
  unsigned short* po = wT + WTN;
  float* pm = (float*)(po + parts * (HD * 32));
  float* pl = pm + parts * 32;

  wtrans<<<dim3(32, 3), 256, 0, stream>>>(wq, wk, wv, wT);
  qkv_proj<<<dim3(128, 3), 256, 0, stream>>>(x, wT, qb, kS, vS);
  const int ablocks = (int)(parts / 4);
  switch (log2S) {
    case 3:
      diff_attn_part<3><<<dim3(ablocks), 256, 0, stream>>>(qb, kS, vS, po, pm, pl);
      diff_merge<3><<<dim3(NB * 128), 256, 0, stream>>>(po, pm, pl, lq1, lq2, lk1, lk2, lnw, out);
      break;
    case 2:
      diff_attn_part<2><<<dim3(ablocks), 256, 0, stream>>>(qb, kS, vS, po, pm, pl);
      diff_merge<2><<<dim3(NB * 128), 256, 0, stream>>>(po, pm, pl, lq1, lq2, lk1, lk2, lnw, out);
      break;
    case 1:
      diff_attn_part<1><<<dim3(ablocks), 256, 0, stream>>>(qb, kS, vS, po, pm, pl);
      diff_merge<1><<<dim3(NB * 128), 256, 0, stream>>>(po, pm, pl, lq1, lq2, lk1, lk2, lnw, out);
      break;
    default:
      diff_attn_part<0><<<dim3(ablocks), 256, 0, stream>>>(qb, kS, vS, po, pm, pl);
      diff_merge<0><<<dim3(NB * 128), 256, 0, stream>>>(po, pm, pl, lq1, lq2, lk1, lk2, lnw, out);
      break;
  }
}

// Round 9
// 90.432 us; speedup vs baseline: 1.0826x; 1.0826x over previous
//
#include <hip/hip_runtime.h>
#include <stdint.h>

#define T_SEQ 4096
#define NB 2
#define D_MODEL 2048
#define HD 128

typedef __attribute__((ext_vector_type(4)))  float f32x4;
typedef __attribute__((ext_vector_type(16))) float f32x16;
typedef __attribute__((ext_vector_type(8)))  short bf16x8;
typedef __attribute__((ext_vector_type(4)))  unsigned u32x4;

#define LAMBDA_INIT 0.7836057665316244f
#define OUT_SCALE   0.21639423346837556f

__device__ __forceinline__ unsigned short f2bf(float f) {
  unsigned int u = __float_as_uint(f);
  u += 0x7FFFu + ((u >> 16) & 1u);
  return (unsigned short)(u >> 16);
}
__device__ __forceinline__ float bf2f(unsigned short h) {
  return __uint_as_float(((unsigned int)h) << 16);
}
__device__ __forceinline__ unsigned cvt_pk_bf16(float a, float b) {
  unsigned r;
  asm("v_cvt_pk_bf16_f32 %0, %1, %2" : "=v"(r) : "v"(a), "v"(b));
  return r;
}
__device__ __forceinline__ void gload16(const void* g, void* l) {
  __builtin_amdgcn_global_load_lds(
      (const __attribute__((address_space(1))) unsigned int*)g,
      (__attribute__((address_space(3))) unsigned int*)l, 16, 0, 0);
}

// ---------------- Kernel 0: pre-pack W into per-k-slab LDS images ---------
__global__ __launch_bounds__(256) void wtrans(
    const float* __restrict__ wq, const float* __restrict__ wk,
    const float* __restrict__ wv, unsigned short* __restrict__ wT)
{
  const int which = blockIdx.y;
  const int s = blockIdx.x;                     // k-slab 0..31
  const float* w = (which == 0) ? wq : ((which == 1) ? wk : wv);
  const float scale = (which == 0) ? 0.125f : 1.0f;
  const int tid = threadIdx.x;
  #pragma unroll
  for (int j = 0; j < 4; ++j) {
    int cell = j * 256 + tid;                   // 0..1023
    int q = cell >> 7, n = cell & 127;
    int kb = s * 64 + q * 8;
    float v[8];
    #pragma unroll
    for (int e = 0; e < 8; ++e) v[e] = w[(size_t)(kb + e) * HD + n] * scale;
    u32x4 pk = { cvt_pk_bf16(v[0], v[1]), cvt_pk_bf16(v[2], v[3]),
                 cvt_pk_bf16(v[4], v[5]), cvt_pk_bf16(v[6], v[7]) };
    *reinterpret_cast<u32x4*>(&wT[(size_t)(which * 32 + s) * 8192 + (size_t)cell * 8]) = pk;
  }
}

// ---------------- Kernel 1: QKV projection -------------------------------
// M=64, N=128, grid (128,3). Counted-vmcnt pipeline: B 3-slab DMA ring
// (2-deep prefetch stays in flight ACROSS barriers), A 2-buf LDS with
// 2-deep register prefetch. Raw s_barrier + positional vmcnt(N).
__global__ __launch_bounds__(256, 2) void qkv_proj(
    const float* __restrict__ x, const unsigned short* __restrict__ wT,
    unsigned short* __restrict__ qb, unsigned short* __restrict__ kS,
    unsigned short* __restrict__ vS)
{
  __shared__ __align__(16) unsigned short Ab[2][4096];   // 16KB
  __shared__ __align__(16) unsigned short Bb[3][8192];   // 48KB
  const int which = blockIdx.y;
  const int m0 = blockIdx.x * 64;
  const int tid = threadIdx.x;
  const int lane = tid & 63, wid = tid >> 6;
  const int wm = wid >> 1, wn = wid & 1;        // wave tile 32(m) x 64(n)
  const int fr = lane & 15, fq = lane >> 4;

  const unsigned short* wslab = wT + (size_t)which * 32 * 8192;
  const int arow = tid & 31, aq = tid >> 5;
  const float* xa = x + (size_t)(m0 + arow) * D_MODEL + aq * 8;
  const float* xb = xa + (size_t)32 * D_MODEL;

  f32x4 acc[2][4];
  #pragma unroll
  for (int i = 0; i < 2; ++i)
    #pragma unroll
    for (int j = 0; j < 4; ++j) acc[i][j] = (f32x4){0.f, 0.f, 0.f, 0.f};

  f32x4 rA0[4], rA1[4];

#define ALOAD(dst, slab) do {                                              \
    const int kn_ = (slab) * 64;                                           \
    dst[0] = *reinterpret_cast<const f32x4*>(xa + kn_);                    \
    dst[1] = *reinterpret_cast<const f32x4*>(xa + kn_ + 4);                \
    dst[2] = *reinterpret_cast<const f32x4*>(xb + kn_);                    \
    dst[3] = *reinterpret_cast<const f32x4*>(xb + kn_ + 4);                \
  } while (0)

#define AWRITE(src, slab) do {                                             \
    unsigned short* ab_ = &Ab[(slab) & 1][0];                              \
    u32x4 c0_ = { cvt_pk_bf16(src[0][0], src[0][1]),                       \
                  cvt_pk_bf16(src[0][2], src[0][3]),                       \
                  cvt_pk_bf16(src[1][0], src[1][1]),                       \
                  cvt_pk_bf16(src[1][2], src[1][3]) };                     \
    u32x4 c1_ = { cvt_pk_bf16(src[2][0], src[2][1]),                       \
                  cvt_pk_bf16(src[2][2], src[2][3]),                       \
                  cvt_pk_bf16(src[3][0], src[3][1]),                       \
                  cvt_pk_bf16(src[3][2], src[3][3]) };                     \
    *reinterpret_cast<u32x4*>(ab_ + (size_t)(aq * 64 + arow) * 8) = c0_;   \
    *reinterpret_cast<u32x4*>(ab_ + (size_t)(aq * 64 + arow + 32) * 8) = c1_; \
  } while (0)

#define BDMA(slab) do {                                                    \
    unsigned short* bb_ = &Bb[(slab) % 3][0] + (wid * 4) * 512;            \
    const unsigned short* gs_ = wslab + (size_t)(slab) * 8192              \
                              + (size_t)(wid * 4) * 512 + (size_t)lane * 8;\
    gload16(gs_,        (char*)(bb_));                                     \
    gload16(gs_ + 512,  (char*)(bb_ + 512));                               \
    gload16(gs_ + 1024, (char*)(bb_ + 1024));                              \
    gload16(gs_ + 1536, (char*)(bb_ + 1536));                              \
  } while (0)

  // prologue (issue order pinned): ALOAD(0); BDMA(0); BDMA(1); ALOAD(1); AWRITE(0)
  ALOAD(rA0, 0);
  __builtin_amdgcn_sched_barrier(0);
  BDMA(0);
  __builtin_amdgcn_sched_barrier(0);
  BDMA(1);
  __builtin_amdgcn_sched_barrier(0);
  ALOAD(rA1, 1);
  __builtin_amdgcn_sched_barrier(0);
  AWRITE(rA0, 0);   // compiler waits rA0 (positional vmcnt(12))

// per-iter: wait(D(t) done) ; barrier ; DMA(t+2) ; AWRITE(t+1) ; ALOAD(t+2) ; MFMA(t)
#define QITER(t, WSRC, LDST) do {                                          \
    if ((t) == 0)      asm volatile("s_waitcnt vmcnt(8) lgkmcnt(0)" ::: "memory");  \
    else if ((t) < 31) asm volatile("s_waitcnt vmcnt(12) lgkmcnt(0)" ::: "memory"); \
    else               asm volatile("s_waitcnt vmcnt(4) lgkmcnt(0)" ::: "memory");  \
    __builtin_amdgcn_s_barrier();                                          \
    __builtin_amdgcn_sched_barrier(0);                                     \
    if ((t) + 2 < 32) BDMA((t) + 2);                                       \
    __builtin_amdgcn_sched_barrier(0);                                     \
    if ((t) + 1 < 32) AWRITE(WSRC, (t) + 1);                               \
    if ((t) + 2 < 32) ALOAD(LDST, (t) + 2);                                \
    __builtin_amdgcn_sched_barrier(0);                                     \
    const unsigned short* bc_ = &Bb[(t) % 3][0];                           \
    const unsigned short* ac_ = &Ab[(t) & 1][0];                           \
    bf16x8 ah_[2][2], bh_[2][4];                                           \
    _Pragma("unroll")                                                      \
    for (int mi = 0; mi < 2; ++mi) {                                       \
      int row = wm * 32 + mi * 16 + fr;                                    \
      ah_[mi][0] = *reinterpret_cast<const bf16x8*>(ac_ + (size_t)(fq * 64 + row) * 8);        \
      ah_[mi][1] = *reinterpret_cast<const bf16x8*>(ac_ + (size_t)((4 + fq) * 64 + row) * 8);  \
    }                                                                      \
    _Pragma("unroll")                                                      \
    for (int ni = 0; ni < 4; ++ni) {                                       \
      int nrow = wn * 64 + ni * 16 + fr;                                   \
      bh_[0][ni] = *reinterpret_cast<const bf16x8*>(bc_ + (size_t)(fq * 128 + nrow) * 8);      \
      bh_[1][ni] = *reinterpret_cast<const bf16x8*>(bc_ + (size_t)((4 + fq) * 128 + nrow) * 8);\
    }                                                                      \
    _Pragma("unroll")                                                      \
    for (int kk = 0; kk < 2; ++kk)                                         \
      _Pragma("unroll")                                                    \
      for (int mi = 0; mi < 2; ++mi)                                       \
        _Pragma("unroll")                                                  \
        for (int ni = 0; ni < 4; ++ni)                                     \
          acc[mi][ni] = __builtin_amdgcn_mfma_f32_16x16x32_bf16(ah_[mi][kk], bh_[kk][ni], acc[mi][ni], 0, 0, 0); \
  } while (0)

  #pragma unroll 1
  for (int th = 0; th < 16; ++th) {
    QITER(2 * th,     rA1, rA0);
    QITER(2 * th + 1, rA0, rA1);
  }
#undef QITER
#undef BDMA
#undef AWRITE
#undef ALOAD

  // epilogue: q row-major (scale folded in wT); K/V fragment scatter
  #pragma unroll
  for (int mi = 0; mi < 2; ++mi)
    #pragma unroll
    for (int ni = 0; ni < 4; ++ni) {
      int n = wn * 64 + ni * 16 + fr;
      #pragma unroll
      for (int r = 0; r < 4; ++r) {
        int m = m0 + wm * 32 + mi * 16 + fq * 4 + r;
        float vv = acc[mi][ni][r];
        int bb = m >> 12, tt = m & 4095;
        int kt = tt >> 5, kvl = tt & 31;
        if (which == 0) {
          qb[(size_t)m * HD + n] = f2bf(vv);
        } else if (which == 1) {
          int g = n >> 6, hl = n & 63;
          int ks = hl >> 4, r8 = (hl >> 3) & 1, e = hl & 7;
          size_t idx = ((((((size_t)bb * 128 + kt) * 2 + g) * 4) + ks) << 9)
                     + (size_t)(kvl + 32 * r8) * 8 + e;
          kS[idx] = f2bf(vv);
        } else {
          int f = kvl >> 4, r8 = (kvl >> 3) & 1, e = kvl & 7;
          int vcb = n >> 5;
          size_t idx = (((((size_t)bb * 128 + kt) * 8) + vcb * 2 + f) << 9)
                     + (size_t)((n & 31) + 32 * r8) * 8 + e;
          vS[idx] = f2bf(vv);
        }
      }
    }
}

// ---------------- Kernel 2: per-wave flash partials (unchanged) -----------
template<int LOG2S>
__global__ __launch_bounds__(256, 2) void diff_attn_part(
    const unsigned short* __restrict__ qb, const unsigned short* __restrict__ kS,
    const unsigned short* __restrict__ vS,
    unsigned short* __restrict__ po, float* __restrict__ pm, float* __restrict__ pl)
{
  constexpr int S = 1 << LOG2S;
  const int tid = threadIdx.x, lane = tid & 63, wid = tid >> 6;
  const int wave_id = blockIdx.x * 4 + wid;
  const int sp = wave_id & (S - 1);
  const int g  = (wave_id >> LOG2S) & 1;
  const int qt_raw = (wave_id >> (LOG2S + 1)) & 127;
  const int b  = wave_id >> (LOG2S + 8);
  const int qt = 127 - qt_raw;                  // heavy-first scheduling
  const int slot = (((b * 128 + qt) * 2 + g) << LOG2S) + sp;
  const int lq = lane & 31, lh = lane >> 5;
  const int q0 = qt * 32;
  const int n  = qt + 1;
  const int kt0 = (n * sp) >> LOG2S;
  const int kt1 = (n * (sp + 1)) >> LOG2S;

  bf16x8 qf[4];
  const unsigned short* qp = qb + ((size_t)b * T_SEQ + q0 + lq) * HD + g * 64 + lh * 8;
  #pragma unroll
  for (int ks = 0; ks < 4; ++ks) qf[ks] = *reinterpret_cast<const bf16x8*>(qp + ks * 16);

  f32x16 acc[4];
  #pragma unroll
  for (int v = 0; v < 4; ++v)
    #pragma unroll
    for (int r = 0; r < 16; ++r) acc[v][r] = 0.f;
  float mrun = -1e30f, lrun = 0.f;

  const unsigned short* kbase = kS + ((size_t)(b * 128) * 2 + g) * 4 * 512 + lane * 8;
  const unsigned short* vbase = vS + (size_t)(b * 128) * 8 * 512 + lane * 8;
  #define KFRAG(kt, ks) (kbase + ((size_t)(kt) * 8 + (ks)) * 512)
  #define VFRAG(kt, f)  (vbase + ((size_t)(kt) * 8 + (f)) * 512)

  bf16x8 kf[4];
  if (kt0 < kt1) {
    #pragma unroll
    for (int ks = 0; ks < 4; ++ks)
      kf[ks] = *reinterpret_cast<const bf16x8*>(KFRAG(kt0, ks));
  }

  for (int kt = kt0; kt < kt1; ++kt) {
    bf16x8 vfa[4], vfb[4];
    #pragma unroll
    for (int vcb = 0; vcb < 4; ++vcb) {
      vfa[vcb] = *reinterpret_cast<const bf16x8*>(VFRAG(kt, vcb * 2));
      vfb[vcb] = *reinterpret_cast<const bf16x8*>(VFRAG(kt, vcb * 2 + 1));
    }
    bf16x8 kfn[4];
    const bool more = (kt + 1 < kt1);
    if (more) {
      #pragma unroll
      for (int ks = 0; ks < 4; ++ks)
        kfn[ks] = *reinterpret_cast<const bf16x8*>(KFRAG(kt + 1, ks));
    }
    f32x16 sc;
    #pragma unroll
    for (int r = 0; r < 16; ++r) sc[r] = 0.f;
    #pragma unroll
    for (int ks = 0; ks < 4; ++ks)
      sc = __builtin_amdgcn_mfma_f32_32x32x16_bf16(kf[ks], qf[ks], sc, 0, 0, 0);

    float p[16];
    if (kt == n - 1) {
      #pragma unroll
      for (int r = 0; r < 16; ++r) {
        int rloc = (r & 3) + 8 * (r >> 2) + 4 * lh;
        p[r] = (rloc > lq) ? -1e30f : sc[r];
      }
    } else {
      #pragma unroll
      for (int r = 0; r < 16; ++r) p[r] = sc[r];
    }
    float t16[16];
    #pragma unroll
    for (int r = 0; r < 16; ++r) t16[r] = p[r];
    #pragma unroll
    for (int st = 8; st >= 1; st >>= 1)
      #pragma unroll
      for (int r = 0; r < 8; ++r)
        if (r < st) t16[r] = fmaxf(t16[r], t16[r + st]);
    float pmax = fmaxf(t16[0], __shfl_xor(t16[0], 32));
    if (__any(pmax > mrun + 8.f)) {
      float mn = fmaxf(mrun, pmax);
      float al = __expf(mrun - mn);
      lrun *= al;
      #pragma unroll
      for (int v = 0; v < 4; ++v)
        #pragma unroll
        for (int r = 0; r < 16; ++r) acc[v][r] *= al;
      mrun = mn;
    }
    float psum;
    {
      float s16[16];
      #pragma unroll
      for (int r = 0; r < 16; ++r) { p[r] = __expf(p[r] - mrun); s16[r] = p[r]; }
      #pragma unroll
      for (int st = 8; st >= 1; st >>= 1)
        #pragma unroll
        for (int r = 0; r < 8; ++r)
          if (r < st) s16[r] += s16[r + st];
      psum = s16[0];
    }
    lrun += psum + __shfl_xor(psum, 32);

    unsigned A0 = cvt_pk_bf16(p[0],  p[1]),  A1 = cvt_pk_bf16(p[2],  p[3]);
    unsigned A2 = cvt_pk_bf16(p[4],  p[5]),  A3 = cvt_pk_bf16(p[6],  p[7]);
    unsigned A4 = cvt_pk_bf16(p[8],  p[9]),  A5 = cvt_pk_bf16(p[10], p[11]);
    unsigned A6 = cvt_pk_bf16(p[12], p[13]), A7 = cvt_pk_bf16(p[14], p[15]);
    unsigned pA0 = (unsigned)__shfl_xor((int)A0, 32);
    unsigned pA1 = (unsigned)__shfl_xor((int)A1, 32);
    unsigned pA2 = (unsigned)__shfl_xor((int)A2, 32);
    unsigned pA3 = (unsigned)__shfl_xor((int)A3, 32);
    unsigned pA4 = (unsigned)__shfl_xor((int)A4, 32);
    unsigned pA5 = (unsigned)__shfl_xor((int)A5, 32);
    unsigned pA6 = (unsigned)__shfl_xor((int)A6, 32);
    unsigned pA7 = (unsigned)__shfl_xor((int)A7, 32);
    u32x4 w0, w1;
    w0[0] = lh ? pA2 : A0;  w0[1] = lh ? pA3 : A1;
    w0[2] = lh ? A2  : pA0; w0[3] = lh ? A3  : pA1;
    w1[0] = lh ? pA6 : A4;  w1[1] = lh ? pA7 : A5;
    w1[2] = lh ? A6  : pA4; w1[3] = lh ? A7  : pA5;
    bf16x8 pb0 = *reinterpret_cast<bf16x8*>(&w0);
    bf16x8 pb1 = *reinterpret_cast<bf16x8*>(&w1);
    #pragma unroll
    for (int vcb = 0; vcb < 4; ++vcb) {
      acc[vcb] = __builtin_amdgcn_mfma_f32_32x32x16_bf16(vfa[vcb], pb0, acc[vcb], 0, 0, 0);
      acc[vcb] = __builtin_amdgcn_mfma_f32_32x32x16_bf16(vfb[vcb], pb1, acc[vcb], 0, 0, 0);
    }
    if (more) {
      #pragma unroll
      for (int ks = 0; ks < 4; ++ks) kf[ks] = kfn[ks];
    }
  }
  #undef KFRAG
  #undef VFRAG
  const size_t pbase = (size_t)slot * (HD * 32);
  #pragma unroll
  for (int vcb = 0; vcb < 4; ++vcb)
    #pragma unroll
    for (int r = 0; r < 16; ++r) {
      int vc = vcb * 32 + (r & 3) + 8 * (r >> 2) + 4 * lh;
      po[pbase + (size_t)vc * 32 + lq] = f2bf(acc[vcb][r]);
    }
  if (lane < 32) {
    pm[slot * 32 + lq] = mrun;
    pl[slot * 32 + lq] = lrun;
  }
}

// ---------------- Kernel 3: merge partials (unchanged) --------------------
template<int LOG2S>
__global__ __launch_bounds__(256) void diff_merge(
    const unsigned short* __restrict__ po, const float* __restrict__ pm,
    const float* __restrict__ pl,
    const float* __restrict__ lq1, const float* __restrict__ lq2,
    const float* __restrict__ lk1, const float* __restrict__ lk2,
    const float* __restrict__ lnw, float* __restrict__ out)
{
  constexpr int S = 1 << LOG2S;
  __shared__ float red[4][32];
  const int tid = threadIdx.x, lane = tid & 63, wid = tid >> 6;
  const int q = tid & 31, vg = tid >> 5;
  const int bq = blockIdx.x;
  const int b = bq >> 7, qt = bq & 127;

  float la = lq1[lane] * lk1[lane];
  float lb = lq2[lane] * lk2[lane];
  #pragma unroll
  for (int off = 32; off >= 1; off >>= 1) {
    la += __shfl_xor(la, off);
    lb += __shfl_xor(lb, off);
  }
  const float lam = __expf(la) - __expf(lb) + LAMBDA_INIT;

  const int p1 = (bq * 2 + 0) * S;
  const int p2 = (bq * 2 + 1) * S;
  float w1[S], w2[S];
  {
    float ms[S];
    #pragma unroll
    for (int s = 0; s < S; ++s) ms[s] = pm[(p1 + s) * 32 + q];
    float M = ms[0];
    #pragma unroll
    for (int s = 1; s < S; ++s) M = fmaxf(M, ms[s]);
    float L = 0.f;
    #pragma unroll
    for (int s = 0; s < S; ++s) { w1[s] = __expf(ms[s] - M); L += w1[s] * pl[(p1 + s) * 32 + q]; }
    float inv = 1.f / L;
    #pragma unroll
    for (int s = 0; s < S; ++s) w1[s] *= inv;
  }
  {
    float ms[S];
    #pragma unroll
    for (int s = 0; s < S; ++s) ms[s] = pm[(p2 + s) * 32 + q];
    float M = ms[0];
    #pragma unroll
    for (int s = 1; s < S; ++s) M = fmaxf(M, ms[s]);
    float L = 0.f;
    #pragma unroll
    for (int s = 0; s < S; ++s) { w2[s] = __expf(ms[s] - M); L += w2[s] * pl[(p2 + s) * 32 + q]; }
    float inv = lam / L;
    #pragma unroll
    for (int s = 0; s < S; ++s) w2[s] *= inv;
  }
  float d[16], ss = 0.f;
  #pragma unroll
  for (int i = 0; i < 16; ++i) {
    int vc = vg * 16 + i;
    float a1 = 0.f, a2 = 0.f;
    #pragma unroll
    for (int s = 0; s < S; ++s) {
      a1 += w1[s] * bf2f(po[(size_t)(p1 + s) * (HD * 32) + (size_t)vc * 32 + q]);
      a2 += w2[s] * bf2f(po[(size_t)(p2 + s) * (HD * 32) + (size_t)vc * 32 + q]);
    }
    d[i] = a1 - a2;
    ss += d[i] * d[i];
  }
  ss += __shfl_xor(ss, 32);
  if (lane < 32) red[wid][q] = ss;
  __syncthreads();
  float tot = red[0][q] + red[1][q] + red[2][q] + red[3][q];
  float rinv = 1.f / sqrtf(tot * (1.0f / HD) + 1e-5f);
  float* op = out + ((size_t)b * T_SEQ + qt * 32 + q) * HD + vg * 16;
  #pragma unroll
  for (int i = 0; i < 16; ++i) op[i] = OUT_SCALE * d[i] * rinv * lnw[vg * 16 + i];
}

extern "C" void kernel_launch(void* const* d_in, const int* in_sizes, int n_in,
                              void* d_out, int out_size, void* d_ws, size_t ws_size,
                              hipStream_t stream) {
  const float* x   = (const float*)d_in[0];
  const float* wq  = (const float*)d_in[1];
  const float* wk  = (const float*)d_in[2];
  const float* wv  = (const float*)d_in[3];
  const float* lq1 = (const float*)d_in[4];
  const float* lq2 = (const float*)d_in[5];
  const float* lk1 = (const float*)d_in[6];
  const float* lk2 = (const float*)d_in[7];
  const float* lnw = (const float*)d_in[8];
  float* out = (float*)d_out;

  const size_t N = (size_t)NB * T_SEQ * HD;     // 1,048,576
  const size_t WTN = (size_t)3 * 32 * 8192;     // 786,432
  int log2S = 3;
  for (; log2S > 0; --log2S) {
    size_t parts = ((size_t)NB * 128 * 2) << log2S;
    size_t need = 3 * N * 2 + WTN * 2 + parts * (HD * 32) * 2 + parts * 32 * 8;
    if (need <= ws_size) break;
  }
  const size_t parts = ((size_t)NB * 128 * 2) << log2S;

  unsigned short* qb = (unsigned short*)d_ws;
  unsigned short* kS = qb + N;
  unsigned short* vS = kS + N;
  unsigned short* wT = vS + N;
  unsigned short* po = wT + WTN;
  float* pm = (float*)(po + parts * (HD * 32));
  float* pl = pm + parts * 32;

  wtrans<<<dim3(32, 3), 256, 0, stream>>>(wq, wk, wv, wT);
  qkv_proj<<<dim3(128, 3), 256, 0, stream>>>(x, wT, qb, kS, vS);
  const int ablocks = (int)(parts / 4);
  switch (log2S) {
    case 3:
      diff_attn_part<3><<<dim3(ablocks), 256, 0, stream>>>(qb, kS, vS, po, pm, pl);
      diff_merge<3><<<dim3(NB * 128), 256, 0, stream>>>(po, pm, pl, lq1, lq2, lk1, lk2, lnw, out);
      break;
    case 2:
      diff_attn_part<2><<<dim3(ablocks), 256, 0, stream>>>(qb, kS, vS, po, pm, pl);
      diff_merge<2><<<dim3(NB * 128), 256, 0, stream>>>(po, pm, pl, lq1, lq2, lk1, lk2, lnw, out);
      break;
    case 1:
      diff_attn_part<1><<<dim3(ablocks), 256, 0, stream>>>(qb, kS, vS, po, pm, pl);
      diff_merge<1><<<dim3(NB * 128), 256, 0, stream>>>(po, pm, pl, lq1, lq2, lk1, lk2, lnw, out);
      break;
    default:
      diff_attn_part<0><<<dim3(ablocks), 256, 0, stream>>>(qb, kS, vS, po, pm, pl);
      diff_merge<0><<<dim3(NB * 128), 256, 0, stream>>>(po, pm, pl, lq1, lq2, lk1, lk2, lnw, out);
      break;
  }
}